// Round 5
// baseline (793.299 us; speedup 1.0000x reference)
//
#include <hip/hip_runtime.h>

#define N_NODES 50000
#define T_STEPS 8
#define C_FEAT  64
#define E_EDGES 800000
#define NBLK_SCAN 49   // ceil(N/1024)
#define DPB 8          // dsts per fused-conv block (6250 blocks exactly)
#define SROW 516       // f32 LDS row stride (512+4 -> bank spread)

typedef __attribute__((ext_vector_type(8))) short short8;
typedef __attribute__((ext_vector_type(4))) float f32x4;

__device__ __forceinline__ unsigned short f2bf(float f) {
    union { float f; unsigned int i; } v; v.f = f;
    unsigned int r = v.i + 0x7fff + ((v.i >> 16) & 1);   // RNE
    return (unsigned short)(r >> 16);
}

// ---------------- prep: both W [512][64] f32 -> WT [64][512] bf16 ----------------
__global__ __launch_bounds__(256) void transpose_w2(const float* __restrict__ W1,
                                                    const float* __restrict__ W2,
                                                    unsigned short* __restrict__ WT1,
                                                    unsigned short* __restrict__ WT2) {
    int i = blockIdx.x * 256 + threadIdx.x;       // 0 .. 2*32768
    const float* W = (i < 32768) ? W1 : W2;
    unsigned short* WT = (i < 32768) ? WT1 : WT2;
    int ii = i & 32767;
    int n = ii >> 9, k = ii & 511;
    WT[ii] = f2bf(W[k * 64 + n]);
}

// ---------------- CSR build: hist -> scan -> scatter ----------------
__global__ __launch_bounds__(256) void hist_dst(const int* __restrict__ dst, int* __restrict__ cnt) {
    int e = blockIdx.x * 256 + threadIdx.x;
    if (e < E_EDGES) atomicAdd(&cnt[dst[e]], 1);
}

__global__ __launch_bounds__(1024) void scan1(int* __restrict__ arr, int* __restrict__ bsum) {
    __shared__ int s[1024];
    int i = blockIdx.x * 1024 + threadIdx.x;
    int v = (i < N_NODES) ? arr[i] : 0;
    s[threadIdx.x] = v;
    __syncthreads();
    int acc = v;
    #pragma unroll
    for (int d = 1; d < 1024; d <<= 1) {
        int other = (threadIdx.x >= d) ? s[threadIdx.x - d] : 0;
        __syncthreads();
        acc += other;
        s[threadIdx.x] = acc;
        __syncthreads();
    }
    if (i < N_NODES) arr[i] = acc - v;               // exclusive (local)
    if (threadIdx.x == 1023) bsum[blockIdx.x] = acc; // block total
}

// one-wave shuffle scan over the 49 block sums
__global__ void scan2(const int* __restrict__ bsum, int* __restrict__ bofs) {
    int lane = threadIdx.x;                          // 64 threads
    int orig = (lane < NBLK_SCAN) ? bsum[lane] : 0;
    int v = orig;
    #pragma unroll
    for (int d = 1; d < 64; d <<= 1) {
        int o = __shfl_up(v, d, 64);
        if (lane >= d) v += o;
    }
    if (lane < NBLK_SCAN) bofs[lane] = v - orig;     // exclusive
}

__global__ __launch_bounds__(256) void scan3(int* __restrict__ arr, const int* __restrict__ bofs) {
    int i = blockIdx.x * 256 + threadIdx.x;
    if (i < N_NODES) arr[i] += bofs[i >> 10];
}

// cursor[d] advances from seg start to seg end; afterwards arr[d] == seg end.
// elist entry: src | t<<16 | (d&7)<<19
__global__ __launch_bounds__(256) void scatter_edges(const int* __restrict__ src,
                                                     const int* __restrict__ dst,
                                                     const int* __restrict__ tix,
                                                     int* __restrict__ cursor,
                                                     int* __restrict__ elist) {
    int e = blockIdx.x * 256 + threadIdx.x;
    if (e >= E_EDGES) return;
    int d = dst[e];
    int pos = atomicAdd(&cursor[d], 1);
    elist[pos] = src[e] | (tix[e] << 16) | ((d & 7) << 19);
}

// ---------------- fused conv: edge-parallel ds_add gather -> MFMA GEMM ----------------
// H[d] = relu(bias + cat[d] @ W); cat accumulated in f32 LDS, branch-free.
__global__ __launch_bounds__(256, 8) void fused_conv(const float* __restrict__ X,            // [N,64] f32
                                                     const unsigned short* __restrict__ WT,  // [64,512] bf16 (W^T)
                                                     const float* __restrict__ bias,         // [64] f32
                                                     const int* __restrict__ segend,
                                                     const int* __restrict__ elist,
                                                     float* __restrict__ H) {                // [N,64] f32
    __shared__ float scat[DPB + 1][SROW];            // row DPB = permanent zero row
    const int tid = threadIdx.x;
    const int dbase = blockIdx.x * DPB;
    const int wave = tid >> 6;
    const int lane = tid & 63;

    // zero the tile (cols 0..511 of all 9 rows)
    for (int i = tid; i < (DPB + 1) * 512; i += 256)
        scat[i >> 9][i & 511] = 0.f;
    __syncthreads();

    // ---- stage 1: edge-parallel gather; half-wave per edge, float2 per lane ----
    {
        const int half = lane >> 5;
        const int j = lane & 31;
        const int s0 = dbase ? segend[dbase - 1] : 0;
        const int s1 = segend[dbase + DPB - 1];
        #pragma unroll 4
        for (int idx = s0 + wave * 2 + half; idx < s1; idx += 8) {
            int p = elist[idx];
            int sidx = p & 0xffff;
            int dl = (p >> 19) & 7;
            int t  = (p >> 16) & 7;
            float2 v = *(const float2*)(X + (size_t)sidx * 64 + j * 2);
            float* base = &scat[dl][t * 64 + j * 2];
            atomicAdd(base, v.x);        // ds_add_f32, fire-and-forget
            atomicAdd(base + 1, v.y);
        }
    }
    __syncthreads();

    // ---- stage 2: [8(+8 zero),512] @ [512,64] via MFMA 16x16x32 bf16 ----
    // A-frag: lane m=lane&15 holds A[m][k=quad*8+u]; rows >=8 read the zero row.
    // B-frag: lane holds B[k=quad*8+u][n=lane&15] from WT[n][k] contiguous rows.
    // C/D: col = lane&15, row = quad*4 + r  (verified m89/m91 mapping)
    const int m = lane & 15;
    const int quad = lane >> 4;
    const int n0 = wave * 16;
    const int row = (m < 8) ? m : DPB;
    f32x4 acc = {0.f, 0.f, 0.f, 0.f};
    const unsigned short* wrow = WT + (size_t)(n0 + m) * 512;
    #pragma unroll
    for (int kc = 0; kc < 16; ++kc) {
        const float* ap = &scat[row][kc * 32 + quad * 8];
        short8 af;
        #pragma unroll
        for (int u = 0; u < 8; ++u) af[u] = (short)f2bf(ap[u]);
        short8 bf = *(const short8*)(wrow + kc * 32 + quad * 8);
        acc = __builtin_amdgcn_mfma_f32_16x16x32_bf16(af, bf, acc, 0, 0, 0);
    }
    if (quad < 2) {                                   // rows 0..7 valid
        const int col = n0 + m;
        const float bcol = bias[col];
        #pragma unroll
        for (int r = 0; r < 4; ++r) {
            int node = dbase + quad * 4 + r;
            H[(size_t)node * 64 + col] = fmaxf(acc[r] + bcol, 0.f);
        }
    }
}

// ---------------- fused adversary MLP + h1 add (f32) ----------------
__global__ __launch_bounds__(256) void adv_fused(const float* __restrict__ h2,
                                                 const float* __restrict__ Wa1,  // [64,128]
                                                 const float* __restrict__ ba1,  // [128]
                                                 const float* __restrict__ Wa2,  // [128,64]
                                                 const float* __restrict__ ba2,  // [64]
                                                 const float* __restrict__ h1,
                                                 float* __restrict__ out) {
    __shared__ float sH[64][68];
    __shared__ float sT[64][132];
    const int nbase = blockIdx.x * 64;
    const int tid = threadIdx.x;
    const int j0 = (tid & 15) * 4;
    const int n0 = (tid >> 4) * 4;

    #pragma unroll
    for (int i = 0; i < 4; ++i) {
        int row  = (tid >> 4) + i * 16;
        int col4 = (tid & 15);
        int node = nbase + row;
        float4 v = make_float4(0.f, 0.f, 0.f, 0.f);
        if (node < N_NODES)
            v = *(const float4*)(h2 + (size_t)node * C_FEAT + col4 * 4);
        *(float4*)&sH[row][col4 * 4] = v;
    }
    __syncthreads();

    #pragma unroll
    for (int half = 0; half < 2; ++half) {
        const int j = half * 64 + j0;
        float acc[4][4] = {};
        #pragma unroll 8
        for (int k = 0; k < 64; ++k) {
            float4 w = *(const float4*)(Wa1 + k * 128 + j);
            float a0 = sH[n0 + 0][k];
            float a1 = sH[n0 + 1][k];
            float a2 = sH[n0 + 2][k];
            float a3 = sH[n0 + 3][k];
            acc[0][0] = fmaf(a0, w.x, acc[0][0]); acc[0][1] = fmaf(a0, w.y, acc[0][1]);
            acc[0][2] = fmaf(a0, w.z, acc[0][2]); acc[0][3] = fmaf(a0, w.w, acc[0][3]);
            acc[1][0] = fmaf(a1, w.x, acc[1][0]); acc[1][1] = fmaf(a1, w.y, acc[1][1]);
            acc[1][2] = fmaf(a1, w.z, acc[1][2]); acc[1][3] = fmaf(a1, w.w, acc[1][3]);
            acc[2][0] = fmaf(a2, w.x, acc[2][0]); acc[2][1] = fmaf(a2, w.y, acc[2][1]);
            acc[2][2] = fmaf(a2, w.z, acc[2][2]); acc[2][3] = fmaf(a2, w.w, acc[2][3]);
            acc[3][0] = fmaf(a3, w.x, acc[3][0]); acc[3][1] = fmaf(a3, w.y, acc[3][1]);
            acc[3][2] = fmaf(a3, w.z, acc[3][2]); acc[3][3] = fmaf(a3, w.w, acc[3][3]);
        }
        float4 b1 = *(const float4*)(ba1 + j);
        #pragma unroll
        for (int i = 0; i < 4; ++i) {
            float4 r;
            r.x = fmaxf(acc[i][0] + b1.x, 0.f);
            r.y = fmaxf(acc[i][1] + b1.y, 0.f);
            r.z = fmaxf(acc[i][2] + b1.z, 0.f);
            r.w = fmaxf(acc[i][3] + b1.w, 0.f);
            *(float4*)&sT[n0 + i][j] = r;
        }
    }
    __syncthreads();

    float acc[4][4] = {};
    #pragma unroll 8
    for (int k = 0; k < 128; ++k) {
        float4 w = *(const float4*)(Wa2 + k * 64 + j0);
        float a0 = sT[n0 + 0][k];
        float a1 = sT[n0 + 1][k];
        float a2 = sT[n0 + 2][k];
        float a3 = sT[n0 + 3][k];
        acc[0][0] = fmaf(a0, w.x, acc[0][0]); acc[0][1] = fmaf(a0, w.y, acc[0][1]);
        acc[0][2] = fmaf(a0, w.z, acc[0][2]); acc[0][3] = fmaf(a0, w.w, acc[0][3]);
        acc[1][0] = fmaf(a1, w.x, acc[1][0]); acc[1][1] = fmaf(a1, w.y, acc[1][1]);
        acc[1][2] = fmaf(a1, w.z, acc[1][2]); acc[1][3] = fmaf(a1, w.w, acc[1][3]);
        acc[2][0] = fmaf(a2, w.x, acc[2][0]); acc[2][1] = fmaf(a2, w.y, acc[2][1]);
        acc[2][2] = fmaf(a2, w.z, acc[2][2]); acc[2][3] = fmaf(a2, w.w, acc[2][3]);
        acc[3][0] = fmaf(a3, w.x, acc[3][0]); acc[3][1] = fmaf(a3, w.y, acc[3][1]);
        acc[3][2] = fmaf(a3, w.z, acc[3][2]); acc[3][3] = fmaf(a3, w.w, acc[3][3]);
    }
    float4 b2 = *(const float4*)(ba2 + j0);
    #pragma unroll
    for (int i = 0; i < 4; ++i) {
        int node = nbase + n0 + i;
        if (node < N_NODES) {
            float4 hh = *(const float4*)(h1 + (size_t)node * C_FEAT + j0);
            float4 r;
            r.x = acc[i][0] + b2.x + hh.x;
            r.y = acc[i][1] + b2.y + hh.y;
            r.z = acc[i][2] + b2.z + hh.z;
            r.w = acc[i][3] + b2.w + hh.w;
            *(float4*)(out + (size_t)node * C_FEAT + j0) = r;
        }
    }
}

extern "C" void kernel_launch(void* const* d_in, const int* in_sizes, int n_in,
                              void* d_out, int out_size, void* d_ws, size_t ws_size,
                              hipStream_t stream) {
    const float* x   = (const float*)d_in[0];
    const int*   ei  = (const int*)d_in[1];
    const int*   tix = (const int*)d_in[2];
    const float* Wt1 = (const float*)d_in[3];
    const float* bt1 = (const float*)d_in[4];
    const float* Wt2 = (const float*)d_in[5];
    const float* bt2 = (const float*)d_in[6];
    const float* Wa1 = (const float*)d_in[7];
    const float* ba1 = (const float*)d_in[8];
    const float* Wa2 = (const float*)d_in[9];
    const float* ba2 = (const float*)d_in[10];
    float* out = (float*)d_out;

    const int* src = ei;
    const int* dst = ei + E_EDGES;

    // workspace (~29 MB)
    float* h1            = (float*)d_ws;                        // [N,64] f32
    float* h2            = h1 + (size_t)N_NODES * 64;           // [N,64] f32
    unsigned short* WT1  = (unsigned short*)(h2 + (size_t)N_NODES * 64);  // [64,512] bf16
    unsigned short* WT2  = WT1 + 64 * 512;
    int*   arr   = (int*)(WT2 + 64 * 512);                      // N: cnt -> offsets -> seg-ends
    int*   bsum  = arr + N_NODES;                               // 64
    int*   bofs  = bsum + 64;                                   // 64
    int*   elist = bofs + 64;                                   // E packed (src | t<<16 | dl<<19)

    const int eBlk = (E_EDGES + 255) / 256;           // 3125
    const int cBlk = N_NODES / DPB;                   // 6250 (exact)
    const int aBlk = (N_NODES + 63) / 64;             // 782

    // ---- prep: W transposes (bf16) ----
    transpose_w2<<<256, 256, 0, stream>>>(Wt1, Wt2, WT1, WT2);

    // ---- CSR build by dst (reused for both convs) ----
    hipMemsetAsync(arr, 0, N_NODES * sizeof(int), stream);
    hist_dst<<<eBlk, 256, 0, stream>>>(dst, arr);
    scan1<<<NBLK_SCAN, 1024, 0, stream>>>(arr, bsum);
    scan2<<<1, 64, 0, stream>>>(bsum, bofs);
    scan3<<<196, 256, 0, stream>>>(arr, bofs);
    scatter_edges<<<eBlk, 256, 0, stream>>>(src, dst, tix, arr, elist);

    // ---- conv1: x -> h1 ; conv2: h1 -> h2 ----
    fused_conv<<<cBlk, 256, 0, stream>>>(x,  WT1, bt1, arr, elist, h1);
    fused_conv<<<cBlk, 256, 0, stream>>>(h1, WT2, bt2, arr, elist, h2);

    // ---- adversary MLP + residual (third conv == h1) ----
    adv_fused<<<aBlk, 256, 0, stream>>>(h2, Wa1, ba1, Wa2, ba2, h1, out);
}

// Round 6
// 338.917 us; speedup vs baseline: 2.3407x; 2.3407x over previous
//
#include <hip/hip_runtime.h>

#define N_NODES 50000
#define T_STEPS 8
#define C_FEAT  64
#define E_EDGES 800000
#define KEYS    (N_NODES * T_STEPS)   // 400000 (dst*8 + t)
#define NBLK1   391                   // ceil(KEYS/1024)
#define DPB     16                    // dsts per fused-conv block -> 16 MFMA rows exactly
#define SPADU   520                   // ushort row stride (1040 B, 16B-aligned)

typedef __attribute__((ext_vector_type(8))) short short8;
typedef __attribute__((ext_vector_type(4))) float f32x4;

__device__ __forceinline__ float bf2f(unsigned short u) {
    union { unsigned int i; float f; } v; v.i = ((unsigned int)u) << 16; return v.f;
}
__device__ __forceinline__ unsigned short f2bf(float f) {
    union { float f; unsigned int i; } v; v.f = f;
    unsigned int r = v.i + 0x7fff + ((v.i >> 16) & 1);   // RNE
    return (unsigned short)(r >> 16);
}

// ---------------- prep: x->bf16, W1/W2 -> WT bf16, all in one ----------------
__global__ __launch_bounds__(256) void prep(const float* __restrict__ x,
                                            const float* __restrict__ W1,
                                            const float* __restrict__ W2,
                                            unsigned short* __restrict__ xb,
                                            unsigned short* __restrict__ WT1,
                                            unsigned short* __restrict__ WT2) {
    int i = blockIdx.x * 256 + threadIdx.x;
    const int NX = N_NODES * 64;
    if (i < NX) {
        xb[i] = f2bf(x[i]);
    } else if (i < NX + 32768) {
        int ii = i - NX;
        int n = ii >> 9, k = ii & 511;
        WT1[ii] = f2bf(W1[k * 64 + n]);
    } else if (i < NX + 65536) {
        int ii = i - NX - 32768;
        int n = ii >> 9, k = ii & 511;
        WT2[ii] = f2bf(W2[k * 64 + n]);
    }
}

// ---------------- CSR build over key = dst*8 + t ----------------
__global__ __launch_bounds__(256) void hist_key(const int* __restrict__ dst,
                                                const int* __restrict__ tix,
                                                int* __restrict__ cnt) {
    int e = blockIdx.x * 256 + threadIdx.x;
    if (e < E_EDGES) atomicAdd(&cnt[dst[e] * 8 + tix[e]], 1);
}

__global__ __launch_bounds__(1024) void scan1(int* __restrict__ arr, int* __restrict__ bsum) {
    __shared__ int s[1024];
    int i = blockIdx.x * 1024 + threadIdx.x;
    int v = (i < KEYS) ? arr[i] : 0;
    s[threadIdx.x] = v;
    __syncthreads();
    int acc = v;
    #pragma unroll
    for (int d = 1; d < 1024; d <<= 1) {
        int other = (threadIdx.x >= d) ? s[threadIdx.x - d] : 0;
        __syncthreads();
        acc += other;
        s[threadIdx.x] = acc;
        __syncthreads();
    }
    if (i < KEYS) arr[i] = acc - v;                  // exclusive (local)
    if (threadIdx.x == 1023) bsum[blockIdx.x] = acc; // block total
}

// one block scans the 391 block sums
__global__ __launch_bounds__(512) void scan2(const int* __restrict__ bsum, int* __restrict__ bofs) {
    __shared__ int s[512];
    int tid = threadIdx.x;
    int v = (tid < NBLK1) ? bsum[tid] : 0;
    s[tid] = v;
    __syncthreads();
    int acc = v;
    #pragma unroll
    for (int d = 1; d < 512; d <<= 1) {
        int other = (tid >= d) ? s[tid - d] : 0;
        __syncthreads();
        acc += other;
        s[tid] = acc;
        __syncthreads();
    }
    if (tid < NBLK1) bofs[tid] = acc - v;            // exclusive
}

__global__ __launch_bounds__(256) void scan3(int* __restrict__ arr, const int* __restrict__ bofs) {
    int i = blockIdx.x * 256 + threadIdx.x;
    if (i < KEYS) arr[i] += bofs[i >> 10];
}

// cursor advances from seg start to seg end; afterwards arr[k] == inclusive end.
// elist entry: src | t<<16 (t recoverable; within a dst, entries sorted by t)
__global__ __launch_bounds__(256) void scatter_edges(const int* __restrict__ src,
                                                     const int* __restrict__ dst,
                                                     const int* __restrict__ tix,
                                                     int* __restrict__ cursor,
                                                     int* __restrict__ elist) {
    int e = blockIdx.x * 256 + threadIdx.x;
    if (e >= E_EDGES) return;
    int t = tix[e];
    int pos = atomicAdd(&cursor[dst[e] * 8 + t], 1);
    elist[pos] = src[e] | (t << 16);
}

// ---------------- fused conv: t-sorted gather (1 acc reg) -> MFMA GEMM ----------------
// H[d] = relu(bias + cat[d] @ W); wave owns 4 dsts, lane = channel.
#define FLUSH(T, V)                                                    \
    if ((T) != cur) { scat[dl][cur * 64 + c] = f2bf(acc); acc = 0.f; cur = (T); } \
    acc += (V);

__global__ __launch_bounds__(256, 8) void fused_conv(const unsigned short* __restrict__ Xb,  // [N,64] bf16
                                                     const unsigned short* __restrict__ WT,  // [64,512] bf16 (W^T)
                                                     const float* __restrict__ bias,         // [64] f32
                                                     const int* __restrict__ segend,         // KEYS inclusive ends
                                                     const int* __restrict__ elist,          // src | t<<16
                                                     float* __restrict__ H,                  // [N,64] f32
                                                     unsigned short* __restrict__ Hb,        // [N,64] bf16
                                                     int writeHb) {
    __shared__ unsigned short scat[DPB][SPADU];
    const int tid = threadIdx.x;
    const int dbase = blockIdx.x * DPB;
    const int wave = tid >> 6;
    const int lane = tid & 63;
    const int c = lane;

    // each wave zeroes its own 4 rows (cols 0..511); no barrier needed before use
    {
        short8 z = {};
        #pragma unroll
        for (int z4 = 0; z4 < 4; ++z4)
            *(short8*)&scat[wave * 4 + z4][lane * 8] = z;
    }

    // ---- stage 1: per-dst linear scan, t-sorted, single accumulator ----
    #pragma unroll
    for (int q = 0; q < 4; ++q) {
        const int dl = wave * 4 + q;
        const int d = dbase + dl;
        int i   = (d == 0) ? 0 : segend[(size_t)d * 8 - 1];
        int end = segend[(size_t)d * 8 + 7];
        int cur = 0;
        float acc = 0.f;
        for (; i + 3 < end; i += 4) {
            int p0 = elist[i];
            int p1 = elist[i + 1];
            int p2 = elist[i + 2];
            int p3 = elist[i + 3];
            float v0 = bf2f(Xb[(size_t)(p0 & 0xffff) * 64 + c]);
            float v1 = bf2f(Xb[(size_t)(p1 & 0xffff) * 64 + c]);
            float v2 = bf2f(Xb[(size_t)(p2 & 0xffff) * 64 + c]);
            float v3 = bf2f(Xb[(size_t)(p3 & 0xffff) * 64 + c]);
            int t0 = __builtin_amdgcn_readfirstlane(p0) >> 16;   // wave-uniform
            int t1 = __builtin_amdgcn_readfirstlane(p1) >> 16;
            int t2 = __builtin_amdgcn_readfirstlane(p2) >> 16;
            int t3 = __builtin_amdgcn_readfirstlane(p3) >> 16;
            FLUSH(t0, v0)
            FLUSH(t1, v1)
            FLUSH(t2, v2)
            FLUSH(t3, v3)
        }
        for (; i < end; ++i) {
            int p0 = elist[i];
            float v0 = bf2f(Xb[(size_t)(p0 & 0xffff) * 64 + c]);
            int t0 = __builtin_amdgcn_readfirstlane(p0) >> 16;
            FLUSH(t0, v0)
        }
        scat[dl][cur * 64 + c] = f2bf(acc);   // final flush (zeros elsewhere pre-filled)
    }
    __syncthreads();

    // ---- stage 2: [16,512] @ [512,64] via MFMA 16x16x32 bf16; wave w owns cols w*16.. ----
    // A-frag: lane m=lane&15 holds A[m][k=quad*8+u]  (A row m = dst dl=m)
    // B-frag: lane holds B[k=quad*8+u][n=lane&15] from WT[n][k] contiguous rows
    // C/D: col = lane&15, row = quad*4 + r  (verified m89/m91 mapping; R4-validated)
    const int m = lane & 15;
    const int quad = lane >> 4;
    const int n0 = wave * 16;
    f32x4 acc4 = {0.f, 0.f, 0.f, 0.f};
    const unsigned short* wrow = WT + (size_t)(n0 + m) * 512;
    #pragma unroll
    for (int kc = 0; kc < 16; ++kc) {
        short8 af = *(const short8*)&scat[m][kc * 32 + quad * 8];
        short8 bf = *(const short8*)(wrow + kc * 32 + quad * 8);
        acc4 = __builtin_amdgcn_mfma_f32_16x16x32_bf16(af, bf, acc4, 0, 0, 0);
    }
    const int col = n0 + m;
    const float bcol = bias[col];
    #pragma unroll
    for (int r = 0; r < 4; ++r) {
        int node = dbase + quad * 4 + r;
        float h = fmaxf(acc4[r] + bcol, 0.f);
        H[(size_t)node * 64 + col] = h;
        if (writeHb) Hb[(size_t)node * 64 + col] = f2bf(h);
    }
}

// ---------------- fused adversary MLP + h1 add (f32) ----------------
__global__ __launch_bounds__(256) void adv_fused(const float* __restrict__ h2,
                                                 const float* __restrict__ Wa1,  // [64,128]
                                                 const float* __restrict__ ba1,  // [128]
                                                 const float* __restrict__ Wa2,  // [128,64]
                                                 const float* __restrict__ ba2,  // [64]
                                                 const float* __restrict__ h1,
                                                 float* __restrict__ out) {
    __shared__ float sH[64][68];
    __shared__ float sT[64][132];
    const int nbase = blockIdx.x * 64;
    const int tid = threadIdx.x;
    const int j0 = (tid & 15) * 4;
    const int n0 = (tid >> 4) * 4;

    #pragma unroll
    for (int i = 0; i < 4; ++i) {
        int row  = (tid >> 4) + i * 16;
        int col4 = (tid & 15);
        int node = nbase + row;
        float4 v = make_float4(0.f, 0.f, 0.f, 0.f);
        if (node < N_NODES)
            v = *(const float4*)(h2 + (size_t)node * C_FEAT + col4 * 4);
        *(float4*)&sH[row][col4 * 4] = v;
    }
    __syncthreads();

    #pragma unroll
    for (int half = 0; half < 2; ++half) {
        const int j = half * 64 + j0;
        float acc[4][4] = {};
        #pragma unroll 8
        for (int k = 0; k < 64; ++k) {
            float4 w = *(const float4*)(Wa1 + k * 128 + j);
            float a0 = sH[n0 + 0][k];
            float a1 = sH[n0 + 1][k];
            float a2 = sH[n0 + 2][k];
            float a3 = sH[n0 + 3][k];
            acc[0][0] = fmaf(a0, w.x, acc[0][0]); acc[0][1] = fmaf(a0, w.y, acc[0][1]);
            acc[0][2] = fmaf(a0, w.z, acc[0][2]); acc[0][3] = fmaf(a0, w.w, acc[0][3]);
            acc[1][0] = fmaf(a1, w.x, acc[1][0]); acc[1][1] = fmaf(a1, w.y, acc[1][1]);
            acc[1][2] = fmaf(a1, w.z, acc[1][2]); acc[1][3] = fmaf(a1, w.w, acc[1][3]);
            acc[2][0] = fmaf(a2, w.x, acc[2][0]); acc[2][1] = fmaf(a2, w.y, acc[2][1]);
            acc[2][2] = fmaf(a2, w.z, acc[2][2]); acc[2][3] = fmaf(a2, w.w, acc[2][3]);
            acc[3][0] = fmaf(a3, w.x, acc[3][0]); acc[3][1] = fmaf(a3, w.y, acc[3][1]);
            acc[3][2] = fmaf(a3, w.z, acc[3][2]); acc[3][3] = fmaf(a3, w.w, acc[3][3]);
        }
        float4 b1 = *(const float4*)(ba1 + j);
        #pragma unroll
        for (int i = 0; i < 4; ++i) {
            float4 r;
            r.x = fmaxf(acc[i][0] + b1.x, 0.f);
            r.y = fmaxf(acc[i][1] + b1.y, 0.f);
            r.z = fmaxf(acc[i][2] + b1.z, 0.f);
            r.w = fmaxf(acc[i][3] + b1.w, 0.f);
            *(float4*)&sT[n0 + i][j] = r;
        }
    }
    __syncthreads();

    float acc[4][4] = {};
    #pragma unroll 8
    for (int k = 0; k < 128; ++k) {
        float4 w = *(const float4*)(Wa2 + k * 64 + j0);
        float a0 = sT[n0 + 0][k];
        float a1 = sT[n0 + 1][k];
        float a2 = sT[n0 + 2][k];
        float a3 = sT[n0 + 3][k];
        acc[0][0] = fmaf(a0, w.x, acc[0][0]); acc[0][1] = fmaf(a0, w.y, acc[0][1]);
        acc[0][2] = fmaf(a0, w.z, acc[0][2]); acc[0][3] = fmaf(a0, w.w, acc[0][3]);
        acc[1][0] = fmaf(a1, w.x, acc[1][0]); acc[1][1] = fmaf(a1, w.y, acc[1][1]);
        acc[1][2] = fmaf(a1, w.z, acc[1][2]); acc[1][3] = fmaf(a1, w.w, acc[1][3]);
        acc[2][0] = fmaf(a2, w.x, acc[2][0]); acc[2][1] = fmaf(a2, w.y, acc[2][1]);
        acc[2][2] = fmaf(a2, w.z, acc[2][2]); acc[2][3] = fmaf(a2, w.w, acc[2][3]);
        acc[3][0] = fmaf(a3, w.x, acc[3][0]); acc[3][1] = fmaf(a3, w.y, acc[3][1]);
        acc[3][2] = fmaf(a3, w.z, acc[3][2]); acc[3][3] = fmaf(a3, w.w, acc[3][3]);
    }
    float4 b2 = *(const float4*)(ba2 + j0);
    #pragma unroll
    for (int i = 0; i < 4; ++i) {
        int node = nbase + n0 + i;
        if (node < N_NODES) {
            float4 hh = *(const float4*)(h1 + (size_t)node * C_FEAT + j0);
            float4 r;
            r.x = acc[i][0] + b2.x + hh.x;
            r.y = acc[i][1] + b2.y + hh.y;
            r.z = acc[i][2] + b2.z + hh.z;
            r.w = acc[i][3] + b2.w + hh.w;
            *(float4*)(out + (size_t)node * C_FEAT + j0) = r;
        }
    }
}

extern "C" void kernel_launch(void* const* d_in, const int* in_sizes, int n_in,
                              void* d_out, int out_size, void* d_ws, size_t ws_size,
                              hipStream_t stream) {
    const float* x   = (const float*)d_in[0];
    const int*   ei  = (const int*)d_in[1];
    const int*   tix = (const int*)d_in[2];
    const float* Wt1 = (const float*)d_in[3];
    const float* bt1 = (const float*)d_in[4];
    const float* Wt2 = (const float*)d_in[5];
    const float* bt2 = (const float*)d_in[6];
    const float* Wa1 = (const float*)d_in[7];
    const float* ba1 = (const float*)d_in[8];
    const float* Wa2 = (const float*)d_in[9];
    const float* ba2 = (const float*)d_in[10];
    float* out = (float*)d_out;

    const int* src = ei;
    const int* dst = ei + E_EDGES;

    // workspace (~44 MB)
    float* h1            = (float*)d_ws;                                  // [N,64] f32
    float* h2            = h1 + (size_t)N_NODES * 64;                     // [N,64] f32
    unsigned short* xb   = (unsigned short*)(h2 + (size_t)N_NODES * 64);  // [N,64] bf16
    unsigned short* h1b  = xb + (size_t)N_NODES * 64;                     // [N,64] bf16
    unsigned short* WT1  = h1b + (size_t)N_NODES * 64;                    // [64,512] bf16
    unsigned short* WT2  = WT1 + 64 * 512;
    int*   segend = (int*)(WT2 + 64 * 512);                               // KEYS
    int*   bsum   = segend + KEYS;                                        // 512
    int*   bofs   = bsum + 512;                                           // 512
    int*   elist  = bofs + 512;                                           // E packed (src | t<<16)

    const int eBlk = (E_EDGES + 255) / 256;               // 3125
    const int cBlk = N_NODES / DPB;                       // 3125 (exact)
    const int aBlk = (N_NODES + 63) / 64;                 // 782
    const int pBlk = (N_NODES * 64 + 65536 + 255) / 256;  // 13013
    const int kBlk = (KEYS + 255) / 256;                  // 1563

    // ---- prep: bf16 x + both W transposes ----
    prep<<<pBlk, 256, 0, stream>>>(x, Wt1, Wt2, xb, WT1, WT2);

    // ---- CSR build over key = dst*8 + t (reused for both convs) ----
    hipMemsetAsync(segend, 0, KEYS * sizeof(int), stream);
    hist_key<<<eBlk, 256, 0, stream>>>(dst, tix, segend);
    scan1<<<NBLK1, 1024, 0, stream>>>(segend, bsum);
    scan2<<<1, 512, 0, stream>>>(bsum, bofs);
    scan3<<<kBlk, 256, 0, stream>>>(segend, bofs);
    scatter_edges<<<eBlk, 256, 0, stream>>>(src, dst, tix, segend, elist);

    // ---- conv1: xb -> h1 (+h1b) ; conv2: h1b -> h2 ----
    fused_conv<<<cBlk, 256, 0, stream>>>(xb,  WT1, bt1, segend, elist, h1, h1b, 1);
    fused_conv<<<cBlk, 256, 0, stream>>>(h1b, WT2, bt2, segend, elist, h2, h1b, 0);

    // ---- adversary MLP + residual (third conv == h1) ----
    adv_fused<<<aBlk, 256, 0, stream>>>(h2, Wa1, ba1, Wa2, ba2, h1, out);
}

// Round 7
// 314.906 us; speedup vs baseline: 2.5192x; 1.0762x over previous
//
#include <hip/hip_runtime.h>

#define N_NODES 50000
#define T_STEPS 8
#define C_FEAT  64
#define E_EDGES 800000
#define KEYS    (N_NODES * T_STEPS)   // 400000 (dst*8 + t)
#define NBLK1   391                   // ceil(KEYS/1024)
#define DPB     16                    // dsts per fused-conv block -> 16 MFMA rows
#define SPADU   520                   // ushort row stride (1040 B, 16B-aligned)
#define PBLK    12756                 // (N*64 + 65536)/256 prep blocks

typedef __attribute__((ext_vector_type(8))) short short8;
typedef __attribute__((ext_vector_type(4))) float f32x4;

__device__ __forceinline__ float bf2f(unsigned short u) {
    union { unsigned int i; float f; } v; v.i = ((unsigned int)u) << 16; return v.f;
}
__device__ __forceinline__ unsigned short f2bf(float f) {
    union { float f; unsigned int i; } v; v.f = f;
    unsigned int r = v.i + 0x7fff + ((v.i >> 16) & 1);   // RNE
    return (unsigned short)(r >> 16);
}

// ---------------- prep (x->bf16, W->WT bf16) + hist, fused via block ranges ----------------
__global__ __launch_bounds__(256) void prep_hist(const float* __restrict__ x,
                                                 const float* __restrict__ W1,
                                                 const float* __restrict__ W2,
                                                 const int* __restrict__ dst,
                                                 const int* __restrict__ tix,
                                                 unsigned short* __restrict__ xb,
                                                 unsigned short* __restrict__ WT1,
                                                 unsigned short* __restrict__ WT2,
                                                 int* __restrict__ cnt) {
    const int b = blockIdx.x;
    if (b < PBLK) {
        int i = b * 256 + threadIdx.x;
        const int NX = N_NODES * 64;
        if (i < NX) {
            xb[i] = f2bf(x[i]);
        } else if (i < NX + 32768) {
            int ii = i - NX;
            int n = ii >> 9, k = ii & 511;
            WT1[ii] = f2bf(W1[k * 64 + n]);
        } else if (i < NX + 65536) {
            int ii = i - NX - 32768;
            int n = ii >> 9, k = ii & 511;
            WT2[ii] = f2bf(W2[k * 64 + n]);
        }
    } else {
        int e = (b - PBLK) * 256 + threadIdx.x;
        if (e < E_EDGES) atomicAdd(&cnt[dst[e] * 8 + tix[e]], 1);
    }
}

// ---------------- scan1: int4/thread + wave shuffle scan (1024 ints per block) ----------------
__global__ __launch_bounds__(256) void scan1(int* __restrict__ arr, int* __restrict__ bsum) {
    __shared__ int wsum[4];
    const int tid = threadIdx.x;
    const int lane = tid & 63;
    const int wave = tid >> 6;
    const int i4 = blockIdx.x * 256 + tid;
    int4 v = make_int4(0, 0, 0, 0);
    const bool ok = (i4 * 4 < KEYS);                 // KEYS % 4 == 0
    if (ok) v = ((const int4*)arr)[i4];
    int s = v.x + v.y + v.z + v.w;
    int sc = s;                                      // inclusive wave scan
    #pragma unroll
    for (int d = 1; d < 64; d <<= 1) {
        int o = __shfl_up(sc, d, 64);
        if (lane >= d) sc += o;
    }
    if (lane == 63) wsum[wave] = sc;
    __syncthreads();
    int wbase = 0;
    #pragma unroll
    for (int w = 0; w < 4; ++w) wbase += (w < wave) ? wsum[w] : 0;
    int base = wbase + sc - s;                       // exclusive prefix of this thread's 4
    int4 o;
    o.x = base;
    o.y = base + v.x;
    o.z = o.y + v.y;
    o.w = o.z + v.z;
    if (ok) ((int4*)arr)[i4] = o;
    if (tid == 255) bsum[blockIdx.x] = wbase + sc;   // block total
}

// one block scans the 391 block sums
__global__ __launch_bounds__(512) void scan2(const int* __restrict__ bsum, int* __restrict__ bofs) {
    __shared__ int s[512];
    int tid = threadIdx.x;
    int v = (tid < NBLK1) ? bsum[tid] : 0;
    s[tid] = v;
    __syncthreads();
    int acc = v;
    #pragma unroll
    for (int d = 1; d < 512; d <<= 1) {
        int other = (tid >= d) ? s[tid - d] : 0;
        __syncthreads();
        acc += other;
        s[tid] = acc;
        __syncthreads();
    }
    if (tid < NBLK1) bofs[tid] = acc - v;            // exclusive
}

__global__ __launch_bounds__(256) void scan3(int* __restrict__ arr, const int* __restrict__ bofs) {
    int i = blockIdx.x * 256 + threadIdx.x;
    if (i < KEYS) arr[i] += bofs[i >> 10];
}

// cursor advances from seg start to seg end; afterwards arr[k] == inclusive end.
// elist entry: src | t<<16 (t-sorted within each dst)
__global__ __launch_bounds__(256) void scatter_edges(const int* __restrict__ src,
                                                     const int* __restrict__ dst,
                                                     const int* __restrict__ tix,
                                                     int* __restrict__ cursor,
                                                     int* __restrict__ elist) {
    int e = blockIdx.x * 256 + threadIdx.x;
    if (e >= E_EDGES) return;
    int t = tix[e];
    int pos = atomicAdd(&cursor[dst[e] * 8 + t], 1);
    elist[pos] = src[e] | (t << 16);
}

// ---------------- fused conv: register-resident edge stream -> MFMA GEMM ----------------
// H[d] = relu(bias + cat[d] @ W); wave owns 4 dsts, lane = channel.
// Per dst: one coalesced 64-entry elist load into pv, readlane-broadcast each edge
// (SGPR src/t), 8 independent Xb gathers in flight, single t-sorted accumulator.
#define FLUSH(T, V)                                                                   \
    { int _t = (T);                                                                   \
      if (_t != cur) { scat[dl][cur * 64 + c] = f2bf(acc); acc = 0.f; cur = _t; }     \
      acc += (V); }

#define EDGE(K)                                                                       \
    int p##K = __builtin_amdgcn_readlane(pv, e + K);                                  \
    float v##K = bf2f(Xb[(size_t)(p##K & 0xffff) * 64 + c]);

__global__ __launch_bounds__(256, 8) void fused_conv(const unsigned short* __restrict__ Xb,  // [N,64] bf16
                                                     const unsigned short* __restrict__ WT,  // [64,512] bf16 (W^T)
                                                     const float* __restrict__ bias,         // [64] f32
                                                     const int* __restrict__ segend,         // KEYS inclusive ends
                                                     const int* __restrict__ elist,          // src | t<<16
                                                     float* __restrict__ H,                  // [N,64] f32
                                                     unsigned short* __restrict__ Hb,        // [N,64] bf16
                                                     int writeHb) {
    __shared__ unsigned short scat[DPB][SPADU];
    const int tid = threadIdx.x;
    const int dbase = blockIdx.x * DPB;
    const int wave = tid >> 6;
    const int lane = tid & 63;
    const int c = lane;

    // each wave zeroes its own 4 rows; it alone writes them in stage 1
    {
        short8 z = {};
        #pragma unroll
        for (int z4 = 0; z4 < 4; ++z4)
            *(short8*)&scat[wave * 4 + z4][lane * 8] = z;
    }

    // ---- stage 1: per-dst t-sorted scan, register-resident edge stream ----
    #pragma unroll
    for (int q = 0; q < 4; ++q) {
        const int dl = wave * 4 + q;
        const int d = dbase + dl;
        int i = (d == 0) ? 0 : segend[d * 8 - 1];
        const int end = segend[d * 8 + 7];
        int cur = 0;
        float acc = 0.f;
        while (i < end) {
            int cnt = end - i;
            cnt = (cnt > 64) ? 64 : cnt;
            int pv = (lane < cnt) ? elist[i + lane] : 0;   // one coalesced load / 64 edges
            int e = 0;
            for (; e + 7 < cnt; e += 8) {
                EDGE(0) EDGE(1) EDGE(2) EDGE(3) EDGE(4) EDGE(5) EDGE(6) EDGE(7)
                FLUSH(p0 >> 16, v0) FLUSH(p1 >> 16, v1)
                FLUSH(p2 >> 16, v2) FLUSH(p3 >> 16, v3)
                FLUSH(p4 >> 16, v4) FLUSH(p5 >> 16, v5)
                FLUSH(p6 >> 16, v6) FLUSH(p7 >> 16, v7)
            }
            for (; e < cnt; ++e) {
                EDGE(0)
                FLUSH(p0 >> 16, v0)
            }
            i += 64;
        }
        scat[dl][cur * 64 + c] = f2bf(acc);   // final flush (other t slots pre-zeroed)
    }
    __syncthreads();

    // ---- stage 2: [16,512] @ [512,64] via MFMA 16x16x32 bf16; wave w owns cols w*16.. ----
    // A-frag: lane m=lane&15 holds A[m][k=quad*8+u]; B from WT[n][k] contiguous rows.
    // C/D: col = lane&15, row = quad*4 + r  (verified m89/m91 mapping; R4/R6-validated)
    const int m = lane & 15;
    const int quad = lane >> 4;
    const int n0 = wave * 16;
    f32x4 acc4 = {0.f, 0.f, 0.f, 0.f};
    const unsigned short* wrow = WT + (size_t)(n0 + m) * 512;
    #pragma unroll
    for (int kc = 0; kc < 16; ++kc) {
        short8 af = *(const short8*)&scat[m][kc * 32 + quad * 8];
        short8 bf = *(const short8*)(wrow + kc * 32 + quad * 8);
        acc4 = __builtin_amdgcn_mfma_f32_16x16x32_bf16(af, bf, acc4, 0, 0, 0);
    }
    const int col = n0 + m;
    const float bcol = bias[col];
    #pragma unroll
    for (int r = 0; r < 4; ++r) {
        int node = dbase + quad * 4 + r;
        float h = fmaxf(acc4[r] + bcol, 0.f);
        H[(size_t)node * 64 + col] = h;
        if (writeHb) Hb[(size_t)node * 64 + col] = f2bf(h);
    }
}

// ---------------- fused adversary MLP + h1 add (f32) ----------------
__global__ __launch_bounds__(256) void adv_fused(const float* __restrict__ h2,
                                                 const float* __restrict__ Wa1,  // [64,128]
                                                 const float* __restrict__ ba1,  // [128]
                                                 const float* __restrict__ Wa2,  // [128,64]
                                                 const float* __restrict__ ba2,  // [64]
                                                 const float* __restrict__ h1,
                                                 float* __restrict__ out) {
    __shared__ float sH[64][68];
    __shared__ float sT[64][132];
    const int nbase = blockIdx.x * 64;
    const int tid = threadIdx.x;
    const int j0 = (tid & 15) * 4;
    const int n0 = (tid >> 4) * 4;

    #pragma unroll
    for (int i = 0; i < 4; ++i) {
        int row  = (tid >> 4) + i * 16;
        int col4 = (tid & 15);
        int node = nbase + row;
        float4 v = make_float4(0.f, 0.f, 0.f, 0.f);
        if (node < N_NODES)
            v = *(const float4*)(h2 + (size_t)node * C_FEAT + col4 * 4);
        *(float4*)&sH[row][col4 * 4] = v;
    }
    __syncthreads();

    #pragma unroll
    for (int half = 0; half < 2; ++half) {
        const int j = half * 64 + j0;
        float acc[4][4] = {};
        #pragma unroll 8
        for (int k = 0; k < 64; ++k) {
            float4 w = *(const float4*)(Wa1 + k * 128 + j);
            float a0 = sH[n0 + 0][k];
            float a1 = sH[n0 + 1][k];
            float a2 = sH[n0 + 2][k];
            float a3 = sH[n0 + 3][k];
            acc[0][0] = fmaf(a0, w.x, acc[0][0]); acc[0][1] = fmaf(a0, w.y, acc[0][1]);
            acc[0][2] = fmaf(a0, w.z, acc[0][2]); acc[0][3] = fmaf(a0, w.w, acc[0][3]);
            acc[1][0] = fmaf(a1, w.x, acc[1][0]); acc[1][1] = fmaf(a1, w.y, acc[1][1]);
            acc[1][2] = fmaf(a1, w.z, acc[1][2]); acc[1][3] = fmaf(a1, w.w, acc[1][3]);
            acc[2][0] = fmaf(a2, w.x, acc[2][0]); acc[2][1] = fmaf(a2, w.y, acc[2][1]);
            acc[2][2] = fmaf(a2, w.z, acc[2][2]); acc[2][3] = fmaf(a2, w.w, acc[2][3]);
            acc[3][0] = fmaf(a3, w.x, acc[3][0]); acc[3][1] = fmaf(a3, w.y, acc[3][1]);
            acc[3][2] = fmaf(a3, w.z, acc[3][2]); acc[3][3] = fmaf(a3, w.w, acc[3][3]);
        }
        float4 b1 = *(const float4*)(ba1 + j);
        #pragma unroll
        for (int i = 0; i < 4; ++i) {
            float4 r;
            r.x = fmaxf(acc[i][0] + b1.x, 0.f);
            r.y = fmaxf(acc[i][1] + b1.y, 0.f);
            r.z = fmaxf(acc[i][2] + b1.z, 0.f);
            r.w = fmaxf(acc[i][3] + b1.w, 0.f);
            *(float4*)&sT[n0 + i][j] = r;
        }
    }
    __syncthreads();

    float acc[4][4] = {};
    #pragma unroll 8
    for (int k = 0; k < 128; ++k) {
        float4 w = *(const float4*)(Wa2 + k * 64 + j0);
        float a0 = sT[n0 + 0][k];
        float a1 = sT[n0 + 1][k];
        float a2 = sT[n0 + 2][k];
        float a3 = sT[n0 + 3][k];
        acc[0][0] = fmaf(a0, w.x, acc[0][0]); acc[0][1] = fmaf(a0, w.y, acc[0][1]);
        acc[0][2] = fmaf(a0, w.z, acc[0][2]); acc[0][3] = fmaf(a0, w.w, acc[0][3]);
        acc[1][0] = fmaf(a1, w.x, acc[1][0]); acc[1][1] = fmaf(a1, w.y, acc[1][1]);
        acc[1][2] = fmaf(a1, w.z, acc[1][2]); acc[1][3] = fmaf(a1, w.w, acc[1][3]);
        acc[2][0] = fmaf(a2, w.x, acc[2][0]); acc[2][1] = fmaf(a2, w.y, acc[2][1]);
        acc[2][2] = fmaf(a2, w.z, acc[2][2]); acc[2][3] = fmaf(a2, w.w, acc[2][3]);
        acc[3][0] = fmaf(a3, w.x, acc[3][0]); acc[3][1] = fmaf(a3, w.y, acc[3][1]);
        acc[3][2] = fmaf(a3, w.z, acc[3][2]); acc[3][3] = fmaf(a3, w.w, acc[3][3]);
    }
    float4 b2 = *(const float4*)(ba2 + j0);
    #pragma unroll
    for (int i = 0; i < 4; ++i) {
        int node = nbase + n0 + i;
        if (node < N_NODES) {
            float4 hh = *(const float4*)(h1 + (size_t)node * C_FEAT + j0);
            float4 r;
            r.x = acc[i][0] + b2.x + hh.x;
            r.y = acc[i][1] + b2.y + hh.y;
            r.z = acc[i][2] + b2.z + hh.z;
            r.w = acc[i][3] + b2.w + hh.w;
            *(float4*)(out + (size_t)node * C_FEAT + j0) = r;
        }
    }
}

extern "C" void kernel_launch(void* const* d_in, const int* in_sizes, int n_in,
                              void* d_out, int out_size, void* d_ws, size_t ws_size,
                              hipStream_t stream) {
    const float* x   = (const float*)d_in[0];
    const int*   ei  = (const int*)d_in[1];
    const int*   tix = (const int*)d_in[2];
    const float* Wt1 = (const float*)d_in[3];
    const float* bt1 = (const float*)d_in[4];
    const float* Wt2 = (const float*)d_in[5];
    const float* bt2 = (const float*)d_in[6];
    const float* Wa1 = (const float*)d_in[7];
    const float* ba1 = (const float*)d_in[8];
    const float* Wa2 = (const float*)d_in[9];
    const float* ba2 = (const float*)d_in[10];
    float* out = (float*)d_out;

    const int* src = ei;
    const int* dst = ei + E_EDGES;

    // workspace (~44 MB)
    float* h1            = (float*)d_ws;                                  // [N,64] f32
    float* h2            = h1 + (size_t)N_NODES * 64;                     // [N,64] f32
    unsigned short* xb   = (unsigned short*)(h2 + (size_t)N_NODES * 64);  // [N,64] bf16
    unsigned short* h1b  = xb + (size_t)N_NODES * 64;                     // [N,64] bf16
    unsigned short* WT1  = h1b + (size_t)N_NODES * 64;                    // [64,512] bf16
    unsigned short* WT2  = WT1 + 64 * 512;
    int*   segend = (int*)(WT2 + 64 * 512);                               // KEYS
    int*   bsum   = segend + KEYS;                                        // 512
    int*   bofs   = bsum + 512;                                           // 512
    int*   elist  = bofs + 512;                                           // E packed (src | t<<16)

    const int eBlk = (E_EDGES + 255) / 256;               // 3125
    const int cBlk = N_NODES / DPB;                       // 3125 (exact)
    const int aBlk = (N_NODES + 63) / 64;                 // 782
    const int kBlk = (KEYS + 255) / 256;                  // 1563

    // ---- CSR hist + prep fused (memset must precede hist atomics) ----
    hipMemsetAsync(segend, 0, KEYS * sizeof(int), stream);
    prep_hist<<<PBLK + eBlk, 256, 0, stream>>>(x, Wt1, Wt2, dst, tix, xb, WT1, WT2, segend);

    // ---- scan + scatter (reused by both convs) ----
    scan1<<<NBLK1, 256, 0, stream>>>(segend, bsum);
    scan2<<<1, 512, 0, stream>>>(bsum, bofs);
    scan3<<<kBlk, 256, 0, stream>>>(segend, bofs);
    scatter_edges<<<eBlk, 256, 0, stream>>>(src, dst, tix, segend, elist);

    // ---- conv1: xb -> h1 (+h1b) ; conv2: h1b -> h2 ----
    fused_conv<<<cBlk, 256, 0, stream>>>(xb,  WT1, bt1, segend, elist, h1, h1b, 1);
    fused_conv<<<cBlk, 256, 0, stream>>>(h1b, WT2, bt2, segend, elist, h2, h1b, 0);

    // ---- adversary MLP + residual (third conv == h1) ----
    adv_fused<<<aBlk, 256, 0, stream>>>(h2, Wa1, ba1, Wa2, ba2, h1, out);
}